// Round 11
// baseline (123.592 us; speedup 1.0000x reference)
//
#include <hip/hip_runtime.h>
#include <math.h>

typedef float f32x4 __attribute__((ext_vector_type(4)));

__device__ __forceinline__ float dot4v(f32x4 a, f32x4 b){
    return a.x*b.x + a.y*b.y + a.z*b.z + a.w*b.w;
}
__device__ __forceinline__ float dot4(float4 a, float4 b){
    return a.x*b.x + a.y*b.y + a.z*b.z + a.w*b.w;
}

// Reduce four per-lane values across the 64-lane wave simultaneously.
// Result: lanes with (lane&3)==j hold sum of aj. 7 shuffles total.
__device__ __forceinline__ float reduce4(float a0, float a1, float a2, float a3, int lane){
    int b0 = lane & 1, b1 = lane & 2;
    float r  = b0 ? a1 : a0;
    float rt = b0 ? a0 : a1;
    r += __shfl_xor(rt, 1);
    float s  = b0 ? a3 : a2;
    float st = b0 ? a2 : a3;
    s += __shfl_xor(st, 1);
    float u  = b1 ? s : r;
    float ut = b1 ? r : s;
    u += __shfl_xor(ut, 2);
    u += __shfl_xor(u, 4);
    u += __shfl_xor(u, 8);
    u += __shfl_xor(u, 16);
    u += __shfl_xor(u, 32);
    return u;   // lane&3 selects which sum
}

// ---------------------------------------------------------------------------
// K1: AvgPool3d 16^3 (R7 best: NT loads + in-block LDS reduce).
// Block 0 additionally zeroes the 4096-float x_proj atomic accumulator
// (stream-ordered before K2 needs it).
// ---------------------------------------------------------------------------
__global__ __launch_bounds__(256) void pool_k(const float* __restrict__ x,
                                              float* __restrict__ seq,
                                              float* __restrict__ xd){
    __shared__ float red[4][8];
    int tid  = threadIdx.x;
    int lane = tid & 63;
    int part = tid >> 6;                      // 0..3
    int cdh  = blockIdx.x;                    // 0..4095
    if (cdh == 0){
        #pragma unroll
        for (int i = 0; i < 16; i++) xd[tid + i * 256] = 0.f;
    }
    int c  = cdh >> 6;
    int od = (cdh >> 3) & 7;
    int oh = cdh & 7;
    int half = lane >> 5;
    int f    = lane & 31;

    const f32x4* px = (const f32x4*)x;
    size_t base = ((size_t)(c * 128 + od * 16) * 128 + (size_t)(oh * 16 + half)) * 32 + f
                + (size_t)part * 4 * 4096;

    float acc = 0.f;
    #pragma unroll
    for (int ii = 0; ii < 4; ii++){
        size_t o = base + (size_t)ii * 4096;
        #pragma unroll
        for (int jj = 0; jj < 8; jj++){
            f32x4 v = __builtin_nontemporal_load(&px[o + (size_t)jj * 64]);
            acc += (v.x + v.y) + (v.z + v.w);
        }
    }
    acc += __shfl_xor(acc, 1);
    acc += __shfl_xor(acc, 2);
    acc += __shfl_xor(acc, 32);
    if (lane < 32 && (lane & 3) == 0) red[part][lane >> 2] = acc;
    __syncthreads();
    if (tid < 8){
        float v = red[0][tid] + red[1][tid] + red[2][tid] + red[3][tid];
        seq[c * 512 + od * 64 + oh * 8 + tid] = v * (1.0f / 4096.0f);
    }
}

// ---------------------------------------------------------------------------
// K2: fused in_proj + conv1d+SiLU + gate + x_proj-partial. 256 blocks x 256.
// Block = 8-e slice x ALL 64 l (wave w does l = 16w..16w+15, the validated
// R10 inproj wave shape). xz lives only in LDS. x-half blocks (e0<1024):
// conv+SiLU -> xsT + LDS, then partial x_proj over their 8 e's, atomicAdd
// into xd[4096] ([f][l] layout = scan's xdT/bcT). z-half blocks: silu->zsT.
// LDS tiles padded [64][9] (stride-8 would be a 16-way bank conflict).
// ---------------------------------------------------------------------------
__global__ __launch_bounds__(256) void fused_k(const float* __restrict__ seq,
                                               const float* __restrict__ Win,
                                               const float* __restrict__ cw,
                                               const float* __restrict__ cb,
                                               const float* __restrict__ Wx,
                                               float* __restrict__ xsT,
                                               float* __restrict__ zsT,
                                               float* __restrict__ xd){
    __shared__ float xzt[64][9];
    __shared__ float xst[64][9];
    int t    = threadIdx.x;
    int lane = t & 63;
    int w    = t >> 6;               // 0..3
    int e0   = blockIdx.x * 8;       // 0..2040
    int l0   = w * 16;

    // ---- phase 1: in_proj, 16l x 8e per wave (R10-validated shape) ----
    {
        const f32x4* S = (const f32x4*)seq;
        f32x4 sa[16], sb[16];
        #pragma unroll
        for (int r = 0; r < 16; r++){
            sa[r] = S[(size_t)(l0 + r) * 128 + lane];
            sb[r] = S[(size_t)(l0 + r) * 128 + lane + 64];
        }
        #pragma unroll 2
        for (int j = 0; j < 8; j++){
            const f32x4* W = (const f32x4*)Win + (size_t)(e0 + j) * 128;
            f32x4 w0 = W[lane], w1 = W[lane + 64];
            float a[16];
            #pragma unroll
            for (int r = 0; r < 16; r++) a[r] = dot4v(w0, sa[r]) + dot4v(w1, sb[r]);
            float u0 = reduce4(a[0],  a[1],  a[2],  a[3],  lane);
            float u1 = reduce4(a[4],  a[5],  a[6],  a[7],  lane);
            float u2 = reduce4(a[8],  a[9],  a[10], a[11], lane);
            float u3 = reduce4(a[12], a[13], a[14], a[15], lane);
            if (lane < 4){
                xzt[l0 + lane][j]      = u0;
                xzt[l0 + 4  + lane][j] = u1;
                xzt[l0 + 8  + lane][j] = u2;
                xzt[l0 + 12 + lane][j] = u3;
            }
        }
    }
    __syncthreads();

    if (e0 < 1024){
        // ---- phase 2x: conv + SiLU (l = idx&63 -> coalesced xsT writes) ----
        #pragma unroll
        for (int jj = 0; jj < 2; jj++){
            int idx = t + jj * 256;
            int l  = idx & 63;
            int e8 = idx >> 6;       // 0..7
            int e  = e0 + e8;
            float v = cb[e];
            #pragma unroll
            for (int tt = 0; tt < 4; tt++){
                int ll = l - 3 + tt;
                if (ll >= 0) v += cw[e * 4 + tt] * xzt[ll][e8];
            }
            v = v / (1.f + expf(-v));
            xst[l][e8] = v;
            xsT[(size_t)e * 64 + l] = v;
        }
        __syncthreads();

        // ---- phase 3: partial x_proj over this block's 8 e's ----
        // thread: l = t>>2, fg = t&3 -> 16 f's; atomicAdd into xd[f*64+l]
        int l  = t >> 2;
        int fg = t & 3;
        float xr[8];
        #pragma unroll
        for (int j = 0; j < 8; j++) xr[j] = xst[l][j];
        #pragma unroll 4
        for (int i = 0; i < 16; i++){
            int f = fg * 16 + i;
            const float* Wr = Wx + (size_t)f * 1024 + e0;
            float p = 0.f;
            #pragma unroll
            for (int j = 0; j < 8; j++) p += xr[j] * Wr[j];
            atomicAdd(&xd[f * 64 + l], p);
        }
    } else {
        // ---- phase 2z: gate silu(z) -> zsT ----
        #pragma unroll
        for (int jj = 0; jj < 2; jj++){
            int idx = t + jj * 256;
            int l  = idx & 63;
            int e8 = idx >> 6;
            float zv = xzt[l][e8];
            zsT[(size_t)(e0 - 1024 + e8) * 64 + l] = zv / (1.f + expf(-zv));
        }
    }
}

// ---------------------------------------------------------------------------
// K3: fused dt_proj+softplus + parallel selective scan + skip + gate.
// Block per e (1024 blocks x 256 thr). lane = timestep l.
// xdT = xd[0..2047] ([k][l]); bcT = xd[2048..4095] (B: s 0..15, C: 16..31).
// ---------------------------------------------------------------------------
__global__ __launch_bounds__(256) void scan_k(const float* __restrict__ xd,
                                              const float* __restrict__ xsT,
                                              const float* __restrict__ zsT,
                                              const float* __restrict__ Wdt,
                                              const float* __restrict__ bdt,
                                              const float* __restrict__ A_log,
                                              const float* __restrict__ Dv,
                                              float* __restrict__ y){
    __shared__ float red[4][64];
    const float* bcT = xd + 2048;
    int e    = blockIdx.x;           // 0..1023
    int lane = threadIdx.x & 63;     // = l
    int w    = threadIdx.x >> 6;     // 0..3

    float acc = bdt[e];
    #pragma unroll 8
    for (int k = 0; k < 32; k++) acc += xd[k * 64 + lane] * Wdt[e * 32 + k];
    float dtv = (acc > 20.f) ? acc : log1pf(expf(acc));
    float xv  = xsT[(size_t)e * 64 + lane];

    float py = 0.f;
    #pragma unroll
    for (int i = 0; i < 4; i++){
        int s = w * 4 + i;
        float A = -expf(A_log[e * 16 + s]);
        float a = expf(dtv * A);
        float b = (dtv * xv) * bcT[s * 64 + lane];
        #pragma unroll
        for (int d = 1; d < 64; d <<= 1){
            float ap = __shfl_up(a, d);
            float bp = __shfl_up(b, d);
            if (lane >= d){ b += a * bp; a *= ap; }
        }
        py += b * bcT[(16 + s) * 64 + lane];
    }
    red[w][lane] = py;
    __syncthreads();
    if (threadIdx.x < 64){
        float tot = red[0][lane] + red[1][lane] + red[2][lane] + red[3][lane];
        float yv = (tot + xv * Dv[e]) * zsT[(size_t)e * 64 + lane];
        y[(size_t)lane * 1024 + e] = yv;
    }
}

// ---------------------------------------------------------------------------
// K4: out_proj (R10 shape): 8l x 8d per wave, 16 MB Wo traffic. 128 blocks.
// ---------------------------------------------------------------------------
__global__ __launch_bounds__(256) void outproj_k(const float* __restrict__ y,
                                                 const float* __restrict__ Wo,
                                                 float* __restrict__ out){
    int lane = threadIdx.x & 63;
    int wid  = blockIdx.x * 4 + (threadIdx.x >> 6);  // 0..511
    int l0 = (wid >> 6) << 3;        // 8 lgroups of 8 rows
    int d0 = (wid & 63) << 3;        // 64 dgroups of 8 d
    const f32x4* Y = (const f32x4*)y;
    f32x4 yr[8][4];
    #pragma unroll
    for (int r = 0; r < 8; r++){
        #pragma unroll
        for (int q = 0; q < 4; q++)
            yr[r][q] = Y[(size_t)(l0 + r) * 256 + q * 64 + lane];
    }
    #pragma unroll 2
    for (int j = 0; j < 8; j++){
        int d = d0 + j;
        const f32x4* W = (const f32x4*)Wo + (size_t)d * 256;
        float a[8] = {0,0,0,0,0,0,0,0};
        #pragma unroll
        for (int q = 0; q < 4; q++){
            f32x4 w = W[q * 64 + lane];
            #pragma unroll
            for (int r = 0; r < 8; r++) a[r] += dot4v(w, yr[r][q]);
        }
        float u0 = reduce4(a[0], a[1], a[2], a[3], lane);
        float u1 = reduce4(a[4], a[5], a[6], a[7], lane);
        if (lane < 4){
            out[(size_t)(l0 + lane) * 512 + d]     = u0;
            out[(size_t)(l0 + 4 + lane) * 512 + d] = u1;
        }
    }
}

// ---------------------------------------------------------------------------
extern "C" void kernel_launch(void* const* d_in, const int* in_sizes, int n_in,
                              void* d_out, int out_size, void* d_ws, size_t ws_size,
                              hipStream_t stream){
    const float* x          = (const float*)d_in[0];
    const float* in_proj_w  = (const float*)d_in[1];
    const float* conv_w     = (const float*)d_in[2];
    const float* conv_b     = (const float*)d_in[3];
    const float* x_proj_w   = (const float*)d_in[4];
    const float* dt_proj_w  = (const float*)d_in[5];
    const float* dt_proj_b  = (const float*)d_in[6];
    const float* A_log      = (const float*)d_in[7];
    const float* Dv         = (const float*)d_in[8];
    const float* out_proj_w = (const float*)d_in[9];
    float* out = (float*)d_out;

    float* ws   = (float*)d_ws;
    float* seq  = ws;            // 64*512   = 32768
    float* xsT  = ws + 32768;    // 1024*64  = 65536
    float* zsT  = ws + 98304;    // 1024*64  = 65536
    float* xd   = ws + 163840;   // 64*64    = 4096 (atomic accumulator)
    float* y    = ws + 167936;   // 64*1024  = 65536

    hipLaunchKernelGGL(pool_k,    dim3(4096), dim3(256), 0, stream, x, seq, xd);
    hipLaunchKernelGGL(fused_k,   dim3(256),  dim3(256), 0, stream, seq, in_proj_w,
                       conv_w, conv_b, x_proj_w, xsT, zsT, xd);
    hipLaunchKernelGGL(scan_k,    dim3(1024), dim3(256), 0, stream, xd, xsT, zsT,
                       dt_proj_w, dt_proj_b, A_log, Dv, y);
    hipLaunchKernelGGL(outproj_k, dim3(128),  dim3(256), 0, stream, y, out_proj_w, out);
}